// Round 11
// baseline (1038.954 us; speedup 1.0000x reference)
//
#include <hip/hip_runtime.h>
#include <hip/hip_bf16.h>
#include <cstdint>

// MMoE: B=16384, F=1024, E=8, U=512, EH=1024/1024, TH=512/256, T=4
#define B_ 16384
#define F_ 1024
#define E_ 8
#define U_ 512
#define EH1_ 1024
#define EH2_ 1024
#define TH1_ 512
#define TH2_ 256
#define T_ 4

typedef __attribute__((ext_vector_type(4))) float f32x4;
typedef __attribute__((ext_vector_type(8))) short bf16x8;
typedef __attribute__((ext_vector_type(4))) short s16x4;

__device__ __forceinline__ short f2bf(float f) {
  union { float f; unsigned u; } v; v.f = f;
  unsigned r = v.u + 0x7fffu + ((v.u >> 16) & 1u);  // RNE
  return (short)(r >> 16);
}
__device__ __forceinline__ float bf2f(short s) {
  union { unsigned u; float f; } v; v.u = ((unsigned)(unsigned short)s) << 16;
  return v.f;
}

__device__ __forceinline__ void gload16(const void* g, void* l) {
  __builtin_amdgcn_global_load_lds(
      (const __attribute__((address_space(1))) void*)g,
      (__attribute__((address_space(3))) void*)l, 16, 0, 0);
}

// ---- fp32 -> (bf16 main, bf16 residual) elementwise, 8/thread ----
__global__ __launch_bounds__(256) void conv_dual(const float* __restrict__ in,
                                                 short* __restrict__ ob,
                                                 short* __restrict__ orr, long n) {
  long i = ((long)blockIdx.x * 256 + threadIdx.x) * 8;
  if (i >= n) return;
  const float4* p = (const float4*)(in + i);
  float4 a = p[0], b = p[1];
  float v[8] = {a.x, a.y, a.z, a.w, b.x, b.y, b.z, b.w};
  bf16x8 o, r;
#pragma unroll
  for (int j = 0; j < 8; j++) {
    short s = f2bf(v[j]);
    o[j] = s;
    r[j] = f2bf(v[j] - bf2f(s));
  }
  *(bf16x8*)(ob + i) = o;
  *(bf16x8*)(orr + i) = r;
}

// ---- fp32 [Z][K][N] -> bf16 [Z][N][K] (transpose-convert) ----
__global__ __launch_bounds__(256) void trans_conv(const float* __restrict__ W,
                                                  short* __restrict__ Wt, int K, int N) {
  __shared__ float tile[32][33];
  const int e = blockIdx.z;
  const int k0 = blockIdx.x * 32, n0 = blockIdx.y * 32;
  const float* We = W + (size_t)e * K * N;
  short* Wte = Wt + (size_t)e * N * K;
  const int tx = threadIdx.x, ty = threadIdx.y;  // block (32,8)
#pragma unroll
  for (int r = 0; r < 32; r += 8)
    tile[ty + r][tx] = We[(size_t)(k0 + ty + r) * N + (n0 + tx)];
  __syncthreads();
#pragma unroll
  for (int r = 0; r < 32; r += 8)
    Wte[(size_t)(n0 + ty + r) * K + (k0 + tx)] = f2bf(tile[tx][ty + r]);
}

// ---- Wg[T][F][E] fp32 -> pair-major bf16 Wp[32][F] + residual Wr[32][F] ----
__global__ __launch_bounds__(256) void trans_wg(const float* __restrict__ Wg,
                                                short* __restrict__ Wp,
                                                short* __restrict__ Wr) {
  int idx = blockIdx.x * 256 + threadIdx.x;  // 32*1024
  int p = idx >> 10, f = idx & 1023;
  int t = p >> 3, e = p & 7;
  float w = Wg[((size_t)t * F_ + f) * E_ + e];
  short wb = f2bf(w);
  Wp[idx] = wb;
  Wr[idx] = f2bf(w - bf2f(wb));
}

// ---- gate logits via 3-term bf16 MFMA + fused softmax over E ----
__global__ __launch_bounds__(256) void glogits(const short* __restrict__ xb,
                                               const short* __restrict__ xr,
                                               const short* __restrict__ Wp,
                                               const short* __restrict__ Wr,
                                               float* __restrict__ gates) {
  const int wid = threadIdx.x >> 6, lane = threadIdx.x & 63;
  const int m0 = blockIdx.x * 64 + wid * 16;
  const int fr = lane & 15, kg = (lane >> 4) * 8;
  f32x4 acc[2];
#pragma unroll
  for (int j = 0; j < 2; j++)
#pragma unroll
    for (int r = 0; r < 4; r++) acc[j][r] = 0.f;

  const short* Aterm[3] = {xb, xb, xr};
  const short* Bterm[3] = {Wp, Wr, Wp};
#pragma unroll
  for (int term = 0; term < 3; ++term) {
    const short* A = Aterm[term] + (size_t)(m0 + fr) * F_ + kg;
    const short* Bt0 = Bterm[term] + (size_t)fr * F_ + kg;
    const short* Bt1 = Bterm[term] + (size_t)(16 + fr) * F_ + kg;
    for (int k0 = 0; k0 < F_; k0 += 32) {
      bf16x8 a = *(const bf16x8*)(A + k0);
      bf16x8 b0 = *(const bf16x8*)(Bt0 + k0);
      bf16x8 b1 = *(const bf16x8*)(Bt1 + k0);
      acc[0] = __builtin_amdgcn_mfma_f32_16x16x32_bf16(a, b0, acc[0], 0, 0, 0);
      acc[1] = __builtin_amdgcn_mfma_f32_16x16x32_bf16(a, b1, acc[1], 0, 0, 0);
    }
  }
  const int cc = lane & 15;
#pragma unroll
  for (int j = 0; j < 2; ++j) {
    const int t = j * 2 + (cc >> 3), e = cc & 7;
#pragma unroll
    for (int r = 0; r < 4; ++r) {
      float s = acc[j][r];
      float mx = s;
      mx = fmaxf(mx, __shfl_xor(mx, 1, 64));
      mx = fmaxf(mx, __shfl_xor(mx, 2, 64));
      mx = fmaxf(mx, __shfl_xor(mx, 4, 64));
      float ex = __expf(s - mx);
      float sm = ex;
      sm += __shfl_xor(sm, 1, 64);
      sm += __shfl_xor(sm, 2, 64);
      sm += __shfl_xor(sm, 4, 64);
      const int b = m0 + (lane >> 4) * 4 + r;
      gates[((size_t)t * B_ + b) * E_ + e] = ex / sm;
    }
  }
}

// ============ 256x256 8-phase GEMM — r9 ledger, FENCES REMOVED (m141 lesson) ============
// Identical slot/vmcnt ledger to round-9 (refcheck-passed). Raw s_barrier only;
// no sched_barrier order-pinning; compiler manages lgkmcnt for the C++ ds reads.
template <int RELU>
__global__ __launch_bounds__(512, 2) void gemm256(const short* __restrict__ A0, size_t sA,
                                                  const short* __restrict__ B0, size_t sB,
                                                  const float* __restrict__ bias0, size_t sBias,
                                                  short* __restrict__ C0, size_t sC,
                                                  int M, int N, int K) {
  // XCD-aware bijective block swizzle (all grids have nwg % 8 == 0)
  unsigned nwg = gridDim.x * gridDim.y * gridDim.z;
  unsigned lid = (blockIdx.z * gridDim.y + blockIdx.y) * gridDim.x + blockIdx.x;
  unsigned sid = (nwg & 7u) ? lid : (lid & 7u) * (nwg >> 3) + (lid >> 3);
  const int bx = sid % gridDim.x;
  unsigned rem = sid / gridDim.x;
  const int by = rem % gridDim.y;
  const int bz = rem / gridDim.y;

  const short* A = A0 + (size_t)bz * sA;
  const short* Bt = B0 + (size_t)bz * sB;
  const float* bias = bias0 + (size_t)bz * sBias;
  short* C = C0 + (size_t)bz * sC;

  __shared__ char lds[131072];  // A:[0,64K) bufs@32K; B:[64K,128K) bufs@32K
  const int tid = threadIdx.x;
  const int wid = tid >> 6, lane = tid & 63;
  const int wr = wid >> 2, wc = wid & 3;
  const int m0g = bx * 256, n0g = by * 256;

  f32x4 acc[8][4];
#pragma unroll
  for (int m = 0; m < 8; m++)
#pragma unroll
    for (int n = 0; n < 4; n++)
#pragma unroll
      for (int r = 0; r < 4; r++) acc[m][n][r] = 0.f;

  // ---- staging: per unit 2 calls x 512 thr x 16B; linear dest, pre-swz src ----
  const int trow = tid >> 3;                            // 0..63
  const int tcolsh = (((tid & 7) ^ (trow & 7)) << 3);   // shorts, inverse-swizzled
  const short* aRow = A + (size_t)(m0g + trow) * K + tcolsh;
  const short* bRow = Bt + (size_t)(n0g + trow) * K + tcolsh;
  const int wpart = wid << 10;

  auto stA = [&](int buf, int u, int kt) {
#pragma unroll
    for (int c = 0; c < 2; ++c)
      gload16(aRow + (size_t)(u * 64 + c * 128) * K + kt * 64,
              lds + buf * 32768 + u * 8192 + c * 16384 + wpart);
  };
  auto stB = [&](int buf, int u, int kt) {
#pragma unroll
    for (int c = 0; c < 2; ++c)
      gload16(bRow + (size_t)(u * 128 + c * 64) * K + kt * 64,
              lds + 65536 + buf * 32768 + u * 16384 + c * 8192 + wpart);
  };

  // ---- frag reads (swizzle is a pure lane function) ----
  const int fr = lane & 15, g = lane >> 4;
  const int swz = (fr & 7) << 4;
  const int rdA = (wr * 128 + fr) * 128;
  const int rdB = (wc * 64 + fr) * 128;
  const int ca0 = (g * 16) ^ swz;
  const int ca1 = (64 + g * 16) ^ swz;

  auto ldA = [&](int buf, int m, int ca) -> bf16x8 {
    return *(const bf16x8*)(lds + buf * 32768 + rdA + m * 2048 + ca);
  };
  auto ldB = [&](int buf, int n, int ca) -> bf16x8 {
    return *(const bf16x8*)(lds + 65536 + buf * 32768 + rdB + n * 2048 + ca);
  };

  const int NT = K >> 6, NI = NT >> 1;

  // ---- prologue: tile0 (4 units) + tile1 {A-u0, B-u0}; vmcnt(4) lands tile0 ----
  stA(0, 0, 0); stB(0, 0, 0); stA(0, 1, 0); stB(0, 1, 0);
  stA(1, 0, 1); stB(1, 0, 1);
  asm volatile("s_waitcnt vmcnt(4)" ::: "memory");
  __builtin_amdgcn_s_barrier();

  bf16x8 a[4], b0[4], b1[4];
#define MFMA16(ACCB, BV)                                                          \
  __builtin_amdgcn_s_setprio(1);                                                  \
  _Pragma("unroll") for (int m = 0; m < 4; ++m)                                   \
      _Pragma("unroll") for (int n = 0; n < 4; ++n)                               \
          acc[ACCB + m][n] =                                                      \
              __builtin_amdgcn_mfma_f32_16x16x32_bf16(a[m], BV[n], acc[ACCB + m][n], 0, 0, 0); \
  __builtin_amdgcn_s_setprio(0);
#define BAR() __builtin_amdgcn_s_barrier();

  for (int i = 0; i < NI; ++i) {
    const int tO = 2 * i + 1;
    const int tE2 = (2 * i + 2 < NT) ? 2 * i + 2 : NT - 2;
    const int tO2 = (2 * i + 3 < NT) ? 2 * i + 3 : NT - 1;

    // p1: buf0 m0-3 ks0 + B ks0
#pragma unroll
    for (int m = 0; m < 4; ++m) a[m] = ldA(0, m, ca0);
#pragma unroll
    for (int n = 0; n < 4; ++n) b0[n] = ldB(0, n, ca0);
    stB(1, 1, tO);
    BAR(); MFMA16(0, b0); BAR();
    // p2: buf0 m0-3 ks1 + B ks1
#pragma unroll
    for (int m = 0; m < 4; ++m) a[m] = ldA(0, m, ca1);
#pragma unroll
    for (int n = 0; n < 4; ++n) b1[n] = ldB(0, n, ca1);
    stA(1, 1, tO);
    BAR(); MFMA16(0, b1); BAR();
    // p3: buf0 m4-7 ks0
#pragma unroll
    for (int m = 0; m < 4; ++m) a[m] = ldA(0, 4 + m, ca0);
    stA(0, 0, tE2);
    BAR(); MFMA16(4, b0); BAR();
    // p4: buf0 m4-7 ks1; vmcnt lands tile 2i+1
#pragma unroll
    for (int m = 0; m < 4; ++m) a[m] = ldA(0, 4 + m, ca1);
    stB(0, 0, tE2);
    BAR(); MFMA16(4, b1);
    asm volatile("s_waitcnt vmcnt(4)" ::: "memory");
    BAR();
    // p5: buf1 m0-3 ks0 + B ks0
#pragma unroll
    for (int m = 0; m < 4; ++m) a[m] = ldA(1, m, ca0);
#pragma unroll
    for (int n = 0; n < 4; ++n) b0[n] = ldB(1, n, ca0);
    stB(0, 1, tE2);
    BAR(); MFMA16(0, b0); BAR();
    // p6: buf1 m0-3 ks1 + B ks1
#pragma unroll
    for (int m = 0; m < 4; ++m) a[m] = ldA(1, m, ca1);
#pragma unroll
    for (int n = 0; n < 4; ++n) b1[n] = ldB(1, n, ca1);
    stA(0, 1, tE2);
    BAR(); MFMA16(0, b1); BAR();
    // p7: buf1 m4-7 ks0
#pragma unroll
    for (int m = 0; m < 4; ++m) a[m] = ldA(1, 4 + m, ca0);
    stA(1, 0, tO2);
    BAR(); MFMA16(4, b0); BAR();
    // p8: buf1 m4-7 ks1; vmcnt lands tile 2i+2
#pragma unroll
    for (int m = 0; m < 4; ++m) a[m] = ldA(1, 4 + m, ca1);
    stB(1, 0, tO2);
    BAR(); MFMA16(4, b1);
    asm volatile("s_waitcnt vmcnt(4)" ::: "memory");
    BAR();
  }
  asm volatile("s_waitcnt vmcnt(0)" ::: "memory");

  // ---- epilogue: C/D map col=lane&15, row=(lane>>4)*4+reg ----
  const int cr4 = (lane >> 4) * 4;
  const int cc = lane & 15;
#pragma unroll
  for (int j = 0; j < 4; ++j) {
    const int col = n0g + wc * 64 + j * 16 + cc;
    const float bv = bias[col];
#pragma unroll
    for (int m = 0; m < 8; ++m) {
      const int row = m0g + wr * 128 + m * 16 + cr4;
#pragma unroll
      for (int r = 0; r < 4; ++r) {
        float v = acc[m][j][r] + bv;
        if (RELU) v = fmaxf(v, 0.f);
        C[(size_t)(row + r) * N + col] = f2bf(v);
      }
    }
  }
#undef MFMA16
#undef BAR
}

// ---- 128x128 z-batched GEMM (r7 proven) — tower layers ----
template <int RELU>
__global__ __launch_bounds__(256, 2) void gemm_bt(const short* __restrict__ A0, size_t sA,
                                                  const short* __restrict__ B0, size_t sB,
                                                  const float* __restrict__ bias0, size_t sBias,
                                                  short* __restrict__ C0, size_t sC,
                                                  int M, int N, int K) {
  const int z = blockIdx.z;
  const short* A = A0 + (size_t)z * sA;
  const short* Bt = B0 + (size_t)z * sB;
  const float* bias = bias0 + (size_t)z * sBias;
  short* C = C0 + (size_t)z * sC;

  __shared__ short As[128 * 64];
  __shared__ short Bs[128 * 64];
  const int tid = threadIdx.x;
  const int wid = tid >> 6;
  const int lane = tid & 63;
  const int m0 = blockIdx.x * 128;
  const int n0 = blockIdx.y * 128;
  const int wm = (wid >> 1) * 64;
  const int wn = (wid & 1) * 64;

  f32x4 acc[4][4];
#pragma unroll
  for (int i = 0; i < 4; i++)
#pragma unroll
    for (int j = 0; j < 4; j++)
#pragma unroll
      for (int r = 0; r < 4; r++) acc[i][j][r] = 0.f;

  const int srow8 = lane >> 3;
  const int scolb = (((lane & 7) ^ srow8) << 4);
  const short* aS = A + (size_t)(m0 + wid * 8 + srow8) * K + (scolb >> 1);
  const short* bS = Bt + (size_t)(n0 + wid * 8 + srow8) * K + (scolb >> 1);
  char* Adst = (char*)As + wid * 1024;
  char* Bdst = (char*)Bs + wid * 1024;

  const int fr = lane & 15;
  const int g = lane >> 4;
  const int swzR = (fr & 7) << 4;
  const char* Ard = (const char*)As + (wm + fr) * 128;
  const char* Brd = (const char*)Bs + (wn + fr) * 128;

  for (int k0 = 0; k0 < K; k0 += 64) {
#pragma unroll
    for (int c = 0; c < 4; ++c) {
      gload16(aS + (size_t)c * 32 * K + k0, Adst + c * 4096);
      gload16(bS + (size_t)c * 32 * K + k0, Bdst + c * 4096);
    }
    __syncthreads();
    {
      const int ca = (g * 16) ^ swzR;
      bf16x8 af[4], bfv[4];
#pragma unroll
      for (int i = 0; i < 4; i++) af[i] = *(const bf16x8*)(Ard + i * 2048 + ca);
#pragma unroll
      for (int j = 0; j < 4; j++) bfv[j] = *(const bf16x8*)(Brd + j * 2048 + ca);
      __builtin_amdgcn_s_setprio(1);
#pragma unroll
      for (int i = 0; i < 4; i++)
#pragma unroll
        for (int j = 0; j < 4; j++)
          acc[i][j] = __builtin_amdgcn_mfma_f32_16x16x32_bf16(af[i], bfv[j], acc[i][j], 0, 0, 0);
      __builtin_amdgcn_s_setprio(0);
    }
    {
      const int ca = (64 + g * 16) ^ swzR;
      bf16x8 af[4], bfv[4];
#pragma unroll
      for (int i = 0; i < 4; i++) af[i] = *(const bf16x8*)(Ard + i * 2048 + ca);
#pragma unroll
      for (int j = 0; j < 4; j++) bfv[j] = *(const bf16x8*)(Brd + j * 2048 + ca);
      __builtin_amdgcn_s_setprio(1);
#pragma unroll
      for (int i = 0; i < 4; i++)
#pragma unroll
        for (int j = 0; j < 4; j++)
          acc[i][j] = __builtin_amdgcn_mfma_f32_16x16x32_bf16(af[i], bfv[j], acc[i][j], 0, 0, 0);
      __builtin_amdgcn_s_setprio(0);
    }
    __syncthreads();
  }

  const int cr4 = (lane >> 4) * 4;
  const int cc = lane & 15;
#pragma unroll
  for (int j = 0; j < 4; j++) {
    const int col = n0 + wn + j * 16 + cc;
    const float bv = bias[col];
#pragma unroll
    for (int i = 0; i < 4; i++) {
      const int row = m0 + wm + i * 16 + cr4;
#pragma unroll
      for (int r = 0; r < 4; r++) {
        float v = acc[i][j][r] + bv;
        if (RELU) v = fmaxf(v, 0.f);
        C[(size_t)(row + r) * N + col] = f2bf(v);
      }
    }
  }
}

// ---- combine (per chunk): ti[t][lb][u] = sum_e gates[t][b0+lb][e]*EO[e][lb][u] ----
__global__ __launch_bounds__(256) void combine_kernel(const short* __restrict__ EO,
                                                      const float* __restrict__ gates,
                                                      short* __restrict__ ti,
                                                      int Bc, int b0) {
  const int idx = blockIdx.x * 256 + threadIdx.x;
  const int lb = idx >> 6;
  const int uc = (idx & 63) * 8;
  float acc[T_][8];
#pragma unroll
  for (int t = 0; t < T_; t++)
#pragma unroll
    for (int j = 0; j < 8; j++) acc[t][j] = 0.f;
#pragma unroll
  for (int e = 0; e < E_; e++) {
    bf16x8 v = *(const bf16x8*)&EO[((size_t)e * Bc + lb) * U_ + uc];
    float f[8];
#pragma unroll
    for (int j = 0; j < 8; j++) f[j] = bf2f(v[j]);
#pragma unroll
    for (int t = 0; t < T_; t++) {
      const float g = gates[((size_t)t * B_ + b0 + lb) * E_ + e];
#pragma unroll
      for (int j = 0; j < 8; j++) acc[t][j] += g * f[j];
    }
  }
#pragma unroll
  for (int t = 0; t < T_; t++) {
    bf16x8 o;
#pragma unroll
    for (int j = 0; j < 8; j++) o[j] = f2bf(acc[t][j]);
    *(bf16x8*)&ti[((size_t)t * Bc + lb) * U_ + uc] = o;
  }
}

// ---- tower3: out[t*B + b0+lb] = dot(G2[t*Bc+lb], Wt3[t]) + bt3[t] ----
__global__ __launch_bounds__(256) void tower3_kernel(const short* __restrict__ G2,
                                                     const float* __restrict__ Wt3,
                                                     const float* __restrict__ bt3,
                                                     float* __restrict__ out,
                                                     int bcShift, int b0) {
  const int wid = threadIdx.x >> 6, lane = threadIdx.x & 63;
  const int rowl = blockIdx.x * 4 + wid;
  const int t = rowl >> bcShift;
  const int lb = rowl & ((1 << bcShift) - 1);
  const short* g = G2 + (size_t)rowl * TH2_;
  s16x4 gv = *(const s16x4*)(g + lane * 4);
  float4 wv = *(const float4*)(Wt3 + t * TH2_ + lane * 4);
  float s = bf2f(gv[0]) * wv.x + bf2f(gv[1]) * wv.y + bf2f(gv[2]) * wv.z + bf2f(gv[3]) * wv.w;
#pragma unroll
  for (int off = 32; off; off >>= 1) s += __shfl_xor(s, off, 64);
  if (lane == 0) out[(size_t)t * B_ + b0 + lb] = s + bt3[t];
}

extern "C" void kernel_launch(void* const* d_in, const int* in_sizes, int n_in,
                              void* d_out, int out_size, void* d_ws, size_t ws_size,
                              hipStream_t stream) {
  const float* x   = (const float*)d_in[0];
  const float* We1 = (const float*)d_in[1];
  const float* be1 = (const float*)d_in[2];
  const float* We2 = (const float*)d_in[3];
  const float* be2 = (const float*)d_in[4];
  const float* We3 = (const float*)d_in[5];
  const float* be3 = (const float*)d_in[6];
  const float* Wg  = (const float*)d_in[7];
  const float* Wt1 = (const float*)d_in[8];
  const float* bt1 = (const float*)d_in[9];
  const float* Wt2 = (const float*)d_in[10];
  const float* bt2 = (const float*)d_in[11];
  const float* Wt3 = (const float*)d_in[12];
  const float* bt3 = (const float*)d_in[13];
  float* out = (float*)d_out;
  (void)in_sizes; (void)n_in; (void)out_size;

  char* ws = (char*)d_ws;
  size_t off = 0;
  auto alloc = [&](size_t bytes) {
    char* p = ws + off;
    off += (bytes + 255) & ~(size_t)255;
    return p;
  };
  // ---- persistent region (~114 MB) ----
  short* We1b  = (short*)alloc((size_t)E_ * F_ * EH1_ * 2);
  short* We2b  = (short*)alloc((size_t)E_ * EH1_ * EH2_ * 2);
  short* We3b  = (short*)alloc((size_t)E_ * EH2_ * U_ * 2);
  short* Wt1b  = (short*)alloc((size_t)T_ * U_ * TH1_ * 2);
  short* Wt2b  = (short*)alloc((size_t)T_ * TH1_ * TH2_ * 2);
  short* Wgp   = (short*)alloc((size_t)32 * F_ * 2);
  short* Wgr   = (short*)alloc((size_t)32 * F_ * 2);
  float* gates = (float*)alloc((size_t)T_ * B_ * E_ * 4);
  short* xb    = (short*)alloc((size_t)B_ * F_ * 2);
  short* xrb   = (short*)alloc((size_t)B_ * F_ * 2);
  const size_t persist = off;

  // ---- chunk sizing: per-row bytes = h1/EO (16384) + h2/{ti,G1,G2} (16384) ----
  int Bc = 16384;
  while (Bc > 256 && persist + (size_t)Bc * 32768 + 65536 > ws_size) Bc >>= 1;
  const int bcShift = __builtin_ctz((unsigned)Bc);

  short* h1 = (short*)alloc((size_t)E_ * Bc * EH1_ * 2);
  short* h2 = (short*)alloc((size_t)E_ * Bc * EH2_ * 2);
  short* EO = h1;
  short* ti = h2;
  short* G1 = h2 + (size_t)Bc * 2048;
  short* G2 = h2 + (size_t)Bc * 4096;

  // ---- one-time conversions ----
  conv_dual<<<(B_ * F_ / 8 + 255) / 256, 256, 0, stream>>>(x, xb, xrb, (long)B_ * F_);
  dim3 tb(32, 8);
  trans_conv<<<dim3(F_ / 32, EH1_ / 32, E_), tb, 0, stream>>>(We1, We1b, F_, EH1_);
  trans_conv<<<dim3(EH1_ / 32, EH2_ / 32, E_), tb, 0, stream>>>(We2, We2b, EH1_, EH2_);
  trans_conv<<<dim3(EH2_ / 32, U_ / 32, E_), tb, 0, stream>>>(We3, We3b, EH2_, U_);
  trans_conv<<<dim3(U_ / 32, TH1_ / 32, T_), tb, 0, stream>>>(Wt1, Wt1b, U_, TH1_);
  trans_conv<<<dim3(TH1_ / 32, TH2_ / 32, T_), tb, 0, stream>>>(Wt2, Wt2b, TH1_, TH2_);
  trans_wg<<<(32 * F_) / 256, 256, 0, stream>>>(Wg, Wgp, Wgr);

  // ---- gates: 3-term MFMA + fused softmax ----
  glogits<<<B_ / 64, 256, 0, stream>>>(xb, xrb, Wgp, Wgr, gates);

  // ---- chunked main pipeline (expert layers on unfenced 8-phase 256²) ----
  for (int b0 = 0; b0 < B_; b0 += Bc) {
    const short* xc = xb + (size_t)b0 * F_;
    gemm256<1><<<dim3(Bc / 256, EH1_ / 256, E_), 512, 0, stream>>>(
        xc, 0, We1b, (size_t)F_ * EH1_, be1, EH1_, h1, (size_t)Bc * EH1_, Bc, EH1_, F_);
    gemm256<1><<<dim3(Bc / 256, EH2_ / 256, E_), 512, 0, stream>>>(
        h1, (size_t)Bc * EH1_, We2b, (size_t)EH1_ * EH2_, be2, EH2_, h2, (size_t)Bc * EH2_,
        Bc, EH2_, EH1_);
    gemm256<0><<<dim3(Bc / 256, U_ / 256, E_), 512, 0, stream>>>(
        h2, (size_t)Bc * EH2_, We3b, (size_t)EH2_ * U_, be3, U_, EO, (size_t)Bc * U_,
        Bc, U_, EH2_);
    combine_kernel<<<(Bc * 64) / 256, 256, 0, stream>>>(EO, gates, ti, Bc, b0);
    gemm_bt<1><<<dim3(Bc / 128, TH1_ / 128, T_), 256, 0, stream>>>(
        ti, (size_t)Bc * U_, Wt1b, (size_t)U_ * TH1_, bt1, TH1_, G1, (size_t)Bc * TH1_,
        Bc, TH1_, U_);
    gemm_bt<1><<<dim3(Bc / 128, TH2_ / 128, T_), 256, 0, stream>>>(
        G1, (size_t)Bc * TH1_, Wt2b, (size_t)TH1_ * TH2_, bt2, TH2_, G2, (size_t)Bc * TH2_,
        Bc, TH2_, TH1_);
    tower3_kernel<<<T_ * Bc / 4, 256, 0, stream>>>(G2, Wt3, bt3, out, bcShift, b0);
  }
}

// Round 12
// 955.922 us; speedup vs baseline: 1.0869x; 1.0869x over previous
//
#include <hip/hip_runtime.h>
#include <hip/hip_bf16.h>
#include <cstdint>

// MMoE: B=16384, F=1024, E=8, U=512, EH=1024/1024, TH=512/256, T=4
#define B_ 16384
#define F_ 1024
#define E_ 8
#define U_ 512
#define EH1_ 1024
#define EH2_ 1024
#define TH1_ 512
#define TH2_ 256
#define T_ 4

typedef __attribute__((ext_vector_type(4))) float f32x4;
typedef __attribute__((ext_vector_type(8))) short bf16x8;
typedef __attribute__((ext_vector_type(4))) short s16x4;

__device__ __forceinline__ short f2bf(float f) {
  union { float f; unsigned u; } v; v.f = f;
  unsigned r = v.u + 0x7fffu + ((v.u >> 16) & 1u);  // RNE
  return (short)(r >> 16);
}
__device__ __forceinline__ float bf2f(short s) {
  union { unsigned u; float f; } v; v.u = ((unsigned)(unsigned short)s) << 16;
  return v.f;
}

__device__ __forceinline__ void gload16(const void* g, void* l) {
  __builtin_amdgcn_global_load_lds(
      (const __attribute__((address_space(1))) void*)g,
      (__attribute__((address_space(3))) void*)l, 16, 0, 0);
}

// ---- fp32 [Z][K][N] -> bf16 [Z][N][K] (transpose-convert) ----
__global__ __launch_bounds__(256) void trans_conv(const float* __restrict__ W,
                                                  short* __restrict__ Wt, int K, int N) {
  __shared__ float tile[32][33];
  const int e = blockIdx.z;
  const int k0 = blockIdx.x * 32, n0 = blockIdx.y * 32;
  const float* We = W + (size_t)e * K * N;
  short* Wte = Wt + (size_t)e * N * K;
  const int tx = threadIdx.x, ty = threadIdx.y;  // block (32,8)
#pragma unroll
  for (int r = 0; r < 32; r += 8)
    tile[ty + r][tx] = We[(size_t)(k0 + ty + r) * N + (n0 + tx)];
  __syncthreads();
#pragma unroll
  for (int r = 0; r < 32; r += 8)
    Wte[(size_t)(n0 + ty + r) * K + (k0 + tx)] = f2bf(tile[tx][ty + r]);
}

// ---- Wg[T][F][E] fp32 -> pair-major bf16 Wp[32][F] + residual Wr[32][F] ----
__global__ __launch_bounds__(256) void trans_wg(const float* __restrict__ Wg,
                                                short* __restrict__ Wp,
                                                short* __restrict__ Wr) {
  int idx = blockIdx.x * 256 + threadIdx.x;  // 32*1024
  int p = idx >> 10, f = idx & 1023;
  int t = p >> 3, e = p & 7;
  float w = Wg[((size_t)t * F_ + f) * E_ + e];
  short wb = f2bf(w);
  Wp[idx] = wb;
  Wr[idx] = f2bf(w - bf2f(wb));
}

// ---- FUSED: x fp32 -> xb bf16 (stored) + gates via 3-term MFMA softmax ----
// One pass over x (67 MB) instead of conv_dual(201 MB) + glogits(134 MB).
// Residual xr lives only in registers (term3 = xr*Wp). Wave = 16 rows;
// lane: fr=row, kg=(lane>>4)*8 k-cols; adjacent lane groups cover full 64-B
// lines of x. 6 MFMA per 32-k step (2 col-frags x 3 terms).
__global__ __launch_bounds__(256) void prep_gates(const float* __restrict__ x,
                                                  short* __restrict__ xb,
                                                  const short* __restrict__ Wp,
                                                  const short* __restrict__ Wr,
                                                  float* __restrict__ gates) {
  const int wid = threadIdx.x >> 6, lane = threadIdx.x & 63;
  const int m0 = blockIdx.x * 64 + wid * 16;
  const int fr = lane & 15, kg = (lane >> 4) * 8;
  f32x4 acc[2];
#pragma unroll
  for (int j = 0; j < 2; j++)
#pragma unroll
    for (int r = 0; r < 4; r++) acc[j][r] = 0.f;

  const float* xrow = x + (size_t)(m0 + fr) * F_ + kg;
  short* xbrow = xb + (size_t)(m0 + fr) * F_ + kg;
  const short* Wp0 = Wp + (size_t)fr * F_ + kg;
  const short* Wp1 = Wp + (size_t)(16 + fr) * F_ + kg;
  const short* Wr0 = Wr + (size_t)fr * F_ + kg;
  const short* Wr1 = Wr + (size_t)(16 + fr) * F_ + kg;

  for (int k0 = 0; k0 < F_; k0 += 32) {
    float4 v0 = *(const float4*)(xrow + k0);
    float4 v1 = *(const float4*)(xrow + k0 + 4);
    float v[8] = {v0.x, v0.y, v0.z, v0.w, v1.x, v1.y, v1.z, v1.w};
    bf16x8 ab, ar;
#pragma unroll
    for (int j = 0; j < 8; j++) {
      short s = f2bf(v[j]);
      ab[j] = s;
      ar[j] = f2bf(v[j] - bf2f(s));
    }
    *(bf16x8*)(xbrow + k0) = ab;
    bf16x8 wp0 = *(const bf16x8*)(Wp0 + k0);
    bf16x8 wp1 = *(const bf16x8*)(Wp1 + k0);
    bf16x8 wr0 = *(const bf16x8*)(Wr0 + k0);
    bf16x8 wr1 = *(const bf16x8*)(Wr1 + k0);
    acc[0] = __builtin_amdgcn_mfma_f32_16x16x32_bf16(ab, wp0, acc[0], 0, 0, 0);
    acc[1] = __builtin_amdgcn_mfma_f32_16x16x32_bf16(ab, wp1, acc[1], 0, 0, 0);
    acc[0] = __builtin_amdgcn_mfma_f32_16x16x32_bf16(ab, wr0, acc[0], 0, 0, 0);
    acc[1] = __builtin_amdgcn_mfma_f32_16x16x32_bf16(ab, wr1, acc[1], 0, 0, 0);
    acc[0] = __builtin_amdgcn_mfma_f32_16x16x32_bf16(ar, wp0, acc[0], 0, 0, 0);
    acc[1] = __builtin_amdgcn_mfma_f32_16x16x32_bf16(ar, wp1, acc[1], 0, 0, 0);
  }

  // C/D: col=lane&15 (pair index), row=(lane>>4)*4+r; pairs p=t*8+e
  const int cc = lane & 15;
#pragma unroll
  for (int j = 0; j < 2; ++j) {
    const int t = j * 2 + (cc >> 3), e = cc & 7;
#pragma unroll
    for (int r = 0; r < 4; ++r) {
      float s = acc[j][r];
      float mx = s;
      mx = fmaxf(mx, __shfl_xor(mx, 1, 64));
      mx = fmaxf(mx, __shfl_xor(mx, 2, 64));
      mx = fmaxf(mx, __shfl_xor(mx, 4, 64));
      float ex = __expf(s - mx);
      float sm = ex;
      sm += __shfl_xor(sm, 1, 64);
      sm += __shfl_xor(sm, 2, 64);
      sm += __shfl_xor(sm, 4, 64);
      const int b = m0 + (lane >> 4) * 4 + r;
      gates[((size_t)t * B_ + b) * E_ + e] = ex / sm;
    }
  }
}

// ---- 128x128 z-batched GEMM, BK=64, conflict-free swizzled LDS (r7 proven) ----
// LDS: As/Bs [128 rows][64 k] bf16 (128-B rows), byte ^= ((row&7)<<4).
// Staged via global_load_lds: linear dest, inverse-swizzled global source.
// Schedule: stage -> sync -> 2x16 MFMA -> sync. ~1000 TF effective at z=8.
template <int RELU>
__global__ __launch_bounds__(256, 2) void gemm_bt(const short* __restrict__ A0, size_t sA,
                                                  const short* __restrict__ B0, size_t sB,
                                                  const float* __restrict__ bias0, size_t sBias,
                                                  short* __restrict__ C0, size_t sC,
                                                  int M, int N, int K) {
  const int z = blockIdx.z;
  const short* A = A0 + (size_t)z * sA;
  const short* Bt = B0 + (size_t)z * sB;
  const float* bias = bias0 + (size_t)z * sBias;
  short* C = C0 + (size_t)z * sC;

  __shared__ short As[128 * 64];  // 16 KB
  __shared__ short Bs[128 * 64];  // 16 KB
  const int tid = threadIdx.x;
  const int wid = tid >> 6;
  const int lane = tid & 63;
  const int m0 = blockIdx.x * 128;
  const int n0 = blockIdx.y * 128;
  const int wm = (wid >> 1) * 64;
  const int wn = (wid & 1) * 64;

  f32x4 acc[4][4];
#pragma unroll
  for (int i = 0; i < 4; i++)
#pragma unroll
    for (int j = 0; j < 4; j++)
#pragma unroll
      for (int r = 0; r < 4; r++) acc[i][j][r] = 0.f;

  const int srow8 = lane >> 3;
  const int scolb = (((lane & 7) ^ srow8) << 4);
  const short* aS = A + (size_t)(m0 + wid * 8 + srow8) * K + (scolb >> 1);
  const short* bS = Bt + (size_t)(n0 + wid * 8 + srow8) * K + (scolb >> 1);
  char* Adst = (char*)As + wid * 1024;  // HW adds lane*16
  char* Bdst = (char*)Bs + wid * 1024;

  const int fr = lane & 15;
  const int g = lane >> 4;
  const int swzR = (fr & 7) << 4;
  const char* Ard = (const char*)As + (wm + fr) * 128;
  const char* Brd = (const char*)Bs + (wn + fr) * 128;

  for (int k0 = 0; k0 < K; k0 += 64) {
#pragma unroll
    for (int c = 0; c < 4; ++c) {
      gload16(aS + (size_t)c * 32 * K + k0, Adst + c * 4096);
      gload16(bS + (size_t)c * 32 * K + k0, Bdst + c * 4096);
    }
    __syncthreads();
    {
      const int ca = (g * 16) ^ swzR;
      bf16x8 af[4], bfv[4];
#pragma unroll
      for (int i = 0; i < 4; i++) af[i] = *(const bf16x8*)(Ard + i * 2048 + ca);
#pragma unroll
      for (int j = 0; j < 4; j++) bfv[j] = *(const bf16x8*)(Brd + j * 2048 + ca);
      __builtin_amdgcn_s_setprio(1);
#pragma unroll
      for (int i = 0; i < 4; i++)
#pragma unroll
        for (int j = 0; j < 4; j++)
          acc[i][j] = __builtin_amdgcn_mfma_f32_16x16x32_bf16(af[i], bfv[j], acc[i][j], 0, 0, 0);
      __builtin_amdgcn_s_setprio(0);
    }
    {
      const int ca = (64 + g * 16) ^ swzR;
      bf16x8 af[4], bfv[4];
#pragma unroll
      for (int i = 0; i < 4; i++) af[i] = *(const bf16x8*)(Ard + i * 2048 + ca);
#pragma unroll
      for (int j = 0; j < 4; j++) bfv[j] = *(const bf16x8*)(Brd + j * 2048 + ca);
      __builtin_amdgcn_s_setprio(1);
#pragma unroll
      for (int i = 0; i < 4; i++)
#pragma unroll
        for (int j = 0; j < 4; j++)
          acc[i][j] = __builtin_amdgcn_mfma_f32_16x16x32_bf16(af[i], bfv[j], acc[i][j], 0, 0, 0);
      __builtin_amdgcn_s_setprio(0);
    }
    __syncthreads();
  }

  // epilogue: C/D map col=lane&15, row=(lane>>4)*4+reg  [m89-verified]
  const int cr4 = (lane >> 4) * 4;
  const int cc = lane & 15;
#pragma unroll
  for (int j = 0; j < 4; j++) {
    const int col = n0 + wn + j * 16 + cc;
    const float bv = bias[col];
#pragma unroll
    for (int i = 0; i < 4; i++) {
      const int row = m0 + wm + i * 16 + cr4;
#pragma unroll
      for (int r = 0; r < 4; r++) {
        float v = acc[i][j][r] + bv;
        if (RELU) v = fmaxf(v, 0.f);
        C[(size_t)(row + r) * N + col] = f2bf(v);
      }
    }
  }
}

// ---- combine (per chunk): ti[t][lb][u] = sum_e gates[t][b0+lb][e]*EO[e][lb][u] ----
__global__ __launch_bounds__(256) void combine_kernel(const short* __restrict__ EO,
                                                      const float* __restrict__ gates,
                                                      short* __restrict__ ti,
                                                      int Bc, int b0) {
  const int idx = blockIdx.x * 256 + threadIdx.x;
  const int lb = idx >> 6;
  const int uc = (idx & 63) * 8;
  float acc[T_][8];
#pragma unroll
  for (int t = 0; t < T_; t++)
#pragma unroll
    for (int j = 0; j < 8; j++) acc[t][j] = 0.f;
#pragma unroll
  for (int e = 0; e < E_; e++) {
    bf16x8 v = *(const bf16x8*)&EO[((size_t)e * Bc + lb) * U_ + uc];
    float f[8];
#pragma unroll
    for (int j = 0; j < 8; j++) f[j] = bf2f(v[j]);
#pragma unroll
    for (int t = 0; t < T_; t++) {
      const float g = gates[((size_t)t * B_ + b0 + lb) * E_ + e];
#pragma unroll
      for (int j = 0; j < 8; j++) acc[t][j] += g * f[j];
    }
  }
#pragma unroll
  for (int t = 0; t < T_; t++) {
    bf16x8 o;
#pragma unroll
    for (int j = 0; j < 8; j++) o[j] = f2bf(acc[t][j]);
    *(bf16x8*)&ti[((size_t)t * Bc + lb) * U_ + uc] = o;
  }
}

// ---- tower3: out[t*B + b0+lb] = dot(G2[t*Bc+lb], Wt3[t]) + bt3[t] ----
__global__ __launch_bounds__(256) void tower3_kernel(const short* __restrict__ G2,
                                                     const float* __restrict__ Wt3,
                                                     const float* __restrict__ bt3,
                                                     float* __restrict__ out,
                                                     int bcShift, int b0) {
  const int wid = threadIdx.x >> 6, lane = threadIdx.x & 63;
  const int rowl = blockIdx.x * 4 + wid;
  const int t = rowl >> bcShift;
  const int lb = rowl & ((1 << bcShift) - 1);
  const short* g = G2 + (size_t)rowl * TH2_;
  s16x4 gv = *(const s16x4*)(g + lane * 4);
  float4 wv = *(const float4*)(Wt3 + t * TH2_ + lane * 4);
  float s = bf2f(gv[0]) * wv.x + bf2f(gv[1]) * wv.y + bf2f(gv[2]) * wv.z + bf2f(gv[3]) * wv.w;
#pragma unroll
  for (int off = 32; off; off >>= 1) s += __shfl_xor(s, off, 64);
  if (lane == 0) out[(size_t)t * B_ + b0 + lb] = s + bt3[t];
}

extern "C" void kernel_launch(void* const* d_in, const int* in_sizes, int n_in,
                              void* d_out, int out_size, void* d_ws, size_t ws_size,
                              hipStream_t stream) {
  const float* x   = (const float*)d_in[0];
  const float* We1 = (const float*)d_in[1];
  const float* be1 = (const float*)d_in[2];
  const float* We2 = (const float*)d_in[3];
  const float* be2 = (const float*)d_in[4];
  const float* We3 = (const float*)d_in[5];
  const float* be3 = (const float*)d_in[6];
  const float* Wg  = (const float*)d_in[7];
  const float* Wt1 = (const float*)d_in[8];
  const float* bt1 = (const float*)d_in[9];
  const float* Wt2 = (const float*)d_in[10];
  const float* bt2 = (const float*)d_in[11];
  const float* Wt3 = (const float*)d_in[12];
  const float* bt3 = (const float*)d_in[13];
  float* out = (float*)d_out;
  (void)in_sizes; (void)n_in; (void)out_size;

  char* ws = (char*)d_ws;
  size_t off = 0;
  auto alloc = [&](size_t bytes) {
    char* p = ws + off;
    off += (bytes + 255) & ~(size_t)255;
    return p;
  };
  // ---- persistent region (~81 MB; xrb eliminated) ----
  short* We1b  = (short*)alloc((size_t)E_ * F_ * EH1_ * 2);
  short* We2b  = (short*)alloc((size_t)E_ * EH1_ * EH2_ * 2);
  short* We3b  = (short*)alloc((size_t)E_ * EH2_ * U_ * 2);
  short* Wt1b  = (short*)alloc((size_t)T_ * U_ * TH1_ * 2);
  short* Wt2b  = (short*)alloc((size_t)T_ * TH1_ * TH2_ * 2);
  short* Wgp   = (short*)alloc((size_t)32 * F_ * 2);
  short* Wgr   = (short*)alloc((size_t)32 * F_ * 2);
  float* gates = (float*)alloc((size_t)T_ * B_ * E_ * 4);
  short* xb    = (short*)alloc((size_t)B_ * F_ * 2);
  const size_t persist = off;

  // ---- chunk sizing: per-row bytes = h1/EO (16384) + h2/{ti,G1,G2} (16384) ----
  int Bc = 16384;
  while (Bc > 256 && persist + (size_t)Bc * 32768 + 65536 > ws_size) Bc >>= 1;
  const int bcShift = __builtin_ctz((unsigned)Bc);

  short* h1 = (short*)alloc((size_t)E_ * Bc * EH1_ * 2);  // also EO overlay
  short* h2 = (short*)alloc((size_t)E_ * Bc * EH2_ * 2);  // also ti/G1/G2 overlay
  short* EO = h1;
  short* ti = h2;                                  // T*Bc*U   = Bc*2048 shorts
  short* G1 = h2 + (size_t)Bc * 2048;              // T*Bc*TH1 = Bc*2048 shorts
  short* G2 = h2 + (size_t)Bc * 4096;              // T*Bc*TH2 = Bc*1024 shorts

  // ---- one-time conversions ----
  dim3 tb(32, 8);
  trans_conv<<<dim3(F_ / 32, EH1_ / 32, E_), tb, 0, stream>>>(We1, We1b, F_, EH1_);
  trans_conv<<<dim3(EH1_ / 32, EH2_ / 32, E_), tb, 0, stream>>>(We2, We2b, EH1_, EH2_);
  trans_conv<<<dim3(EH2_ / 32, U_ / 32, E_), tb, 0, stream>>>(We3, We3b, EH2_, U_);
  trans_conv<<<dim3(U_ / 32, TH1_ / 32, T_), tb, 0, stream>>>(Wt1, Wt1b, U_, TH1_);
  trans_conv<<<dim3(TH1_ / 32, TH2_ / 32, T_), tb, 0, stream>>>(Wt2, Wt2b, TH1_, TH2_);
  trans_wg<<<(32 * F_) / 256, 256, 0, stream>>>(Wg, Wgp, Wgr);

  // ---- fused x->bf16 conversion + 3-term MFMA gates ----
  prep_gates<<<B_ / 64, 256, 0, stream>>>(x, xb, Wgp, Wgr, gates);

  // ---- chunked main pipeline (z-batched BK=64 swizzled GEMMs, r7) ----
  for (int b0 = 0; b0 < B_; b0 += Bc) {
    const short* xc = xb + (size_t)b0 * F_;
    gemm_bt<1><<<dim3(Bc / 128, EH1_ / 128, E_), 256, 0, stream>>>(
        xc, 0, We1b, (size_t)F_ * EH1_, be1, EH1_, h1, (size_t)Bc * EH1_, Bc, EH1_, F_);
    gemm_bt<1><<<dim3(Bc / 128, EH2_ / 128, E_), 256, 0, stream>>>(
        h1, (size_t)Bc * EH1_, We2b, (size_t)EH1_ * EH2_, be2, EH2_, h2, (size_t)Bc * EH2_,
        Bc, EH2_, EH1_);
    gemm_bt<0><<<dim3(Bc / 128, U_ / 128, E_), 256, 0, stream>>>(
        h2, (size_t)Bc * EH2_, We3b, (size_t)EH2_ * U_, be3, U_, EO, (size_t)Bc * U_,
        Bc, U_, EH2_);
    combine_kernel<<<(Bc * 64) / 256, 256, 0, stream>>>(EO, gates, ti, Bc, b0);
    gemm_bt<1><<<dim3(Bc / 128, TH1_ / 128, T_), 256, 0, stream>>>(
        ti, (size_t)Bc * U_, Wt1b, (size_t)U_ * TH1_, bt1, TH1_, G1, (size_t)Bc * TH1_,
        Bc, TH1_, U_);
    gemm_bt<1><<<dim3(Bc / 128, TH2_ / 128, T_), 256, 0, stream>>>(
        G1, (size_t)Bc * TH1_, Wt2b, (size_t)TH1_ * TH2_, bt2, TH2_, G2, (size_t)Bc * TH2_,
        Bc, TH2_, TH1_);
    tower3_kernel<<<T_ * Bc / 4, 256, 0, stream>>>(G2, Wt3, bt3, out, bcShift, b0);
  }
}

// Round 13
// 949.050 us; speedup vs baseline: 1.0947x; 1.0072x over previous
//
#include <hip/hip_runtime.h>
#include <hip/hip_bf16.h>
#include <cstdint>

// MMoE: B=16384, F=1024, E=8, U=512, EH=1024/1024, TH=512/256, T=4
#define B_ 16384
#define F_ 1024
#define E_ 8
#define U_ 512
#define EH1_ 1024
#define EH2_ 1024
#define TH1_ 512
#define TH2_ 256
#define T_ 4

typedef __attribute__((ext_vector_type(4))) float f32x4;
typedef __attribute__((ext_vector_type(8))) short bf16x8;

__device__ __forceinline__ short f2bf(float f) {
  union { float f; unsigned u; } v; v.f = f;
  unsigned r = v.u + 0x7fffu + ((v.u >> 16) & 1u);  // RNE
  return (short)(r >> 16);
}
__device__ __forceinline__ float bf2f(short s) {
  union { unsigned u; float f; } v; v.u = ((unsigned)(unsigned short)s) << 16;
  return v.f;
}

__device__ __forceinline__ void gload16(const void* g, void* l) {
  __builtin_amdgcn_global_load_lds(
      (const __attribute__((address_space(1))) void*)g,
      (__attribute__((address_space(3))) void*)l, 16, 0, 0);
}

// ---- fp32 [Z][K][N] -> bf16 [Z][N][K] (transpose-convert) ----
__global__ __launch_bounds__(256) void trans_conv(const float* __restrict__ W,
                                                  short* __restrict__ Wt, int K, int N) {
  __shared__ float tile[32][33];
  const int e = blockIdx.z;
  const int k0 = blockIdx.x * 32, n0 = blockIdx.y * 32;
  const float* We = W + (size_t)e * K * N;
  short* Wte = Wt + (size_t)e * N * K;
  const int tx = threadIdx.x, ty = threadIdx.y;  // block (32,8)
#pragma unroll
  for (int r = 0; r < 32; r += 8)
    tile[ty + r][tx] = We[(size_t)(k0 + ty + r) * N + (n0 + tx)];
  __syncthreads();
#pragma unroll
  for (int r = 0; r < 32; r += 8)
    Wte[(size_t)(n0 + ty + r) * K + (k0 + tx)] = f2bf(tile[tx][ty + r]);
}

// ---- Wg[T][F][E] fp32 -> pair-major bf16 Wp[32][F] + residual Wr[32][F] ----
__global__ __launch_bounds__(256) void trans_wg(const float* __restrict__ Wg,
                                                short* __restrict__ Wp,
                                                short* __restrict__ Wr) {
  int idx = blockIdx.x * 256 + threadIdx.x;  // 32*1024
  int p = idx >> 10, f = idx & 1023;
  int t = p >> 3, e = p & 7;
  float w = Wg[((size_t)t * F_ + f) * E_ + e];
  short wb = f2bf(w);
  Wp[idx] = wb;
  Wr[idx] = f2bf(w - bf2f(wb));
}

// ---- FUSED: x fp32 -> xb bf16 (stored) + gates via 3-term MFMA softmax ----
__global__ __launch_bounds__(256) void prep_gates(const float* __restrict__ x,
                                                  short* __restrict__ xb,
                                                  const short* __restrict__ Wp,
                                                  const short* __restrict__ Wr,
                                                  float* __restrict__ gates) {
  const int wid = threadIdx.x >> 6, lane = threadIdx.x & 63;
  const int m0 = blockIdx.x * 64 + wid * 16;
  const int fr = lane & 15, kg = (lane >> 4) * 8;
  f32x4 acc[2];
#pragma unroll
  for (int j = 0; j < 2; j++)
#pragma unroll
    for (int r = 0; r < 4; r++) acc[j][r] = 0.f;

  const float* xrow = x + (size_t)(m0 + fr) * F_ + kg;
  short* xbrow = xb + (size_t)(m0 + fr) * F_ + kg;
  const short* Wp0 = Wp + (size_t)fr * F_ + kg;
  const short* Wp1 = Wp + (size_t)(16 + fr) * F_ + kg;
  const short* Wr0 = Wr + (size_t)fr * F_ + kg;
  const short* Wr1 = Wr + (size_t)(16 + fr) * F_ + kg;

  for (int k0 = 0; k0 < F_; k0 += 32) {
    float4 v0 = *(const float4*)(xrow + k0);
    float4 v1 = *(const float4*)(xrow + k0 + 4);
    float v[8] = {v0.x, v0.y, v0.z, v0.w, v1.x, v1.y, v1.z, v1.w};
    bf16x8 ab, ar;
#pragma unroll
    for (int j = 0; j < 8; j++) {
      short s = f2bf(v[j]);
      ab[j] = s;
      ar[j] = f2bf(v[j] - bf2f(s));
    }
    *(bf16x8*)(xbrow + k0) = ab;
    bf16x8 wp0 = *(const bf16x8*)(Wp0 + k0);
    bf16x8 wp1 = *(const bf16x8*)(Wp1 + k0);
    bf16x8 wr0 = *(const bf16x8*)(Wr0 + k0);
    bf16x8 wr1 = *(const bf16x8*)(Wr1 + k0);
    acc[0] = __builtin_amdgcn_mfma_f32_16x16x32_bf16(ab, wp0, acc[0], 0, 0, 0);
    acc[1] = __builtin_amdgcn_mfma_f32_16x16x32_bf16(ab, wp1, acc[1], 0, 0, 0);
    acc[0] = __builtin_amdgcn_mfma_f32_16x16x32_bf16(ab, wr0, acc[0], 0, 0, 0);
    acc[1] = __builtin_amdgcn_mfma_f32_16x16x32_bf16(ab, wr1, acc[1], 0, 0, 0);
    acc[0] = __builtin_amdgcn_mfma_f32_16x16x32_bf16(ar, wp0, acc[0], 0, 0, 0);
    acc[1] = __builtin_amdgcn_mfma_f32_16x16x32_bf16(ar, wp1, acc[1], 0, 0, 0);
  }

  const int cc = lane & 15;
#pragma unroll
  for (int j = 0; j < 2; ++j) {
    const int t = j * 2 + (cc >> 3), e = cc & 7;
#pragma unroll
    for (int r = 0; r < 4; ++r) {
      float s = acc[j][r];
      float mx = s;
      mx = fmaxf(mx, __shfl_xor(mx, 1, 64));
      mx = fmaxf(mx, __shfl_xor(mx, 2, 64));
      mx = fmaxf(mx, __shfl_xor(mx, 4, 64));
      float ex = __expf(s - mx);
      float sm = ex;
      sm += __shfl_xor(sm, 1, 64);
      sm += __shfl_xor(sm, 2, 64);
      sm += __shfl_xor(sm, 4, 64);
      const int b = m0 + (lane >> 4) * 4 + r;
      gates[((size_t)t * B_ + b) * E_ + e] = ex / sm;
    }
  }
}

// ---- 128x128 z-batched GEMM, BK=64, conflict-free swizzled LDS (r7 proven) ----
template <int RELU>
__global__ __launch_bounds__(256, 2) void gemm_bt(const short* __restrict__ A0, size_t sA,
                                                  const short* __restrict__ B0, size_t sB,
                                                  const float* __restrict__ bias0, size_t sBias,
                                                  short* __restrict__ C0, size_t sC,
                                                  int M, int N, int K) {
  const int z = blockIdx.z;
  const short* A = A0 + (size_t)z * sA;
  const short* Bt = B0 + (size_t)z * sB;
  const float* bias = bias0 + (size_t)z * sBias;
  short* C = C0 + (size_t)z * sC;

  __shared__ short As[128 * 64];
  __shared__ short Bs[128 * 64];
  const int tid = threadIdx.x;
  const int wid = tid >> 6;
  const int lane = tid & 63;
  const int m0 = blockIdx.x * 128;
  const int n0 = blockIdx.y * 128;
  const int wm = (wid >> 1) * 64;
  const int wn = (wid & 1) * 64;

  f32x4 acc[4][4];
#pragma unroll
  for (int i = 0; i < 4; i++)
#pragma unroll
    for (int j = 0; j < 4; j++)
#pragma unroll
      for (int r = 0; r < 4; r++) acc[i][j][r] = 0.f;

  const int srow8 = lane >> 3;
  const int scolb = (((lane & 7) ^ srow8) << 4);
  const short* aS = A + (size_t)(m0 + wid * 8 + srow8) * K + (scolb >> 1);
  const short* bS = Bt + (size_t)(n0 + wid * 8 + srow8) * K + (scolb >> 1);
  char* Adst = (char*)As + wid * 1024;
  char* Bdst = (char*)Bs + wid * 1024;

  const int fr = lane & 15;
  const int g = lane >> 4;
  const int swzR = (fr & 7) << 4;
  const char* Ard = (const char*)As + (wm + fr) * 128;
  const char* Brd = (const char*)Bs + (wn + fr) * 128;

  for (int k0 = 0; k0 < K; k0 += 64) {
#pragma unroll
    for (int c = 0; c < 4; ++c) {
      gload16(aS + (size_t)c * 32 * K + k0, Adst + c * 4096);
      gload16(bS + (size_t)c * 32 * K + k0, Bdst + c * 4096);
    }
    __syncthreads();
    {
      const int ca = (g * 16) ^ swzR;
      bf16x8 af[4], bfv[4];
#pragma unroll
      for (int i = 0; i < 4; i++) af[i] = *(const bf16x8*)(Ard + i * 2048 + ca);
#pragma unroll
      for (int j = 0; j < 4; j++) bfv[j] = *(const bf16x8*)(Brd + j * 2048 + ca);
      __builtin_amdgcn_s_setprio(1);
#pragma unroll
      for (int i = 0; i < 4; i++)
#pragma unroll
        for (int j = 0; j < 4; j++)
          acc[i][j] = __builtin_amdgcn_mfma_f32_16x16x32_bf16(af[i], bfv[j], acc[i][j], 0, 0, 0);
      __builtin_amdgcn_s_setprio(0);
    }
    {
      const int ca = (64 + g * 16) ^ swzR;
      bf16x8 af[4], bfv[4];
#pragma unroll
      for (int i = 0; i < 4; i++) af[i] = *(const bf16x8*)(Ard + i * 2048 + ca);
#pragma unroll
      for (int j = 0; j < 4; j++) bfv[j] = *(const bf16x8*)(Brd + j * 2048 + ca);
      __builtin_amdgcn_s_setprio(1);
#pragma unroll
      for (int i = 0; i < 4; i++)
#pragma unroll
        for (int j = 0; j < 4; j++)
          acc[i][j] = __builtin_amdgcn_mfma_f32_16x16x32_bf16(af[i], bfv[j], acc[i][j], 0, 0, 0);
      __builtin_amdgcn_s_setprio(0);
    }
    __syncthreads();
  }

  const int cr4 = (lane >> 4) * 4;
  const int cc = lane & 15;
#pragma unroll
  for (int j = 0; j < 4; j++) {
    const int col = n0 + wn + j * 16 + cc;
    const float bv = bias[col];
#pragma unroll
    for (int i = 0; i < 4; i++) {
      const int row = m0 + wm + i * 16 + cr4;
#pragma unroll
      for (int r = 0; r < 4; r++) {
        float v = acc[i][j][r] + bv;
        if (RELU) v = fmaxf(v, 0.f);
        C[(size_t)(row + r) * N + col] = f2bf(v);
      }
    }
  }
}

// ---- combine: ti[(t*tiStride + tiOff + lb)*U + u] = sum_e gates[t][b0+lb][e]*EO[e][lb][u]
__global__ __launch_bounds__(256) void combine_kernel(const short* __restrict__ EO,
                                                      const float* __restrict__ gates,
                                                      short* __restrict__ ti,
                                                      int Bc, int b0, int tiStride, int tiOff) {
  const int idx = blockIdx.x * 256 + threadIdx.x;
  const int lb = idx >> 6;
  const int uc = (idx & 63) * 8;
  float acc[T_][8];
#pragma unroll
  for (int t = 0; t < T_; t++)
#pragma unroll
    for (int j = 0; j < 8; j++) acc[t][j] = 0.f;
#pragma unroll
  for (int e = 0; e < E_; e++) {
    bf16x8 v = *(const bf16x8*)&EO[((size_t)e * Bc + lb) * U_ + uc];
    float f[8];
#pragma unroll
    for (int j = 0; j < 8; j++) f[j] = bf2f(v[j]);
#pragma unroll
    for (int t = 0; t < T_; t++) {
      const float g = gates[((size_t)t * B_ + b0 + lb) * E_ + e];
#pragma unroll
      for (int j = 0; j < 8; j++) acc[t][j] += g * f[j];
    }
  }
#pragma unroll
  for (int t = 0; t < T_; t++) {
    bf16x8 o;
#pragma unroll
    for (int j = 0; j < 8; j++) o[j] = f2bf(acc[t][j]);
    *(bf16x8*)&ti[((size_t)t * tiStride + tiOff + lb) * U_ + uc] = o;
  }
}

// ---- FUSED tower2+tower3: out[t*B + b0 + m0+row] =
//      dot(relu(G1row @ Wt2[t]^T + bt2[t]), Wt3[t]) + bt3[t]
// 8 waves (2Mx4N), tile 128x256, K=512; G2 lives only in registers.
__global__ __launch_bounds__(512, 1) void wt23(const short* __restrict__ G1, size_t sG1,
                                               const short* __restrict__ W2,
                                               const float* __restrict__ b2,
                                               const float* __restrict__ w3,
                                               const float* __restrict__ b3,
                                               float* __restrict__ out, int b0) {
  const int t = blockIdx.z;
  const short* A = G1 + (size_t)t * sG1;
  const short* Bt = W2 + (size_t)t * TH1_ * TH2_;  // [256][512] bf16

  __shared__ short As[128 * 64];   // 16 KB
  __shared__ short Bs[256 * 64];   // 32 KB
  __shared__ float ps[4][128];     // 2 KB
  const int tid = threadIdx.x, wid = tid >> 6, lane = tid & 63;
  const int m0 = blockIdx.x * 128;
  const int wm = (wid >> 2) * 64, wn = (wid & 3) * 64;

  f32x4 acc[4][4];
#pragma unroll
  for (int i = 0; i < 4; i++)
#pragma unroll
    for (int j = 0; j < 4; j++)
#pragma unroll
      for (int r = 0; r < 4; r++) acc[i][j][r] = 0.f;

  // staging (r10-verified pattern): 512 thr x 16B = 64 rows x 128B per call
  const int trow = tid >> 3;
  const int scolb = (((tid & 7) ^ (trow & 7)) << 4);
  const short* aS = A + (size_t)(m0 + trow) * TH1_ + (scolb >> 1);
  const short* bS = Bt + (size_t)trow * TH1_ + (scolb >> 1);
  char* Adst = (char*)As + wid * 1024;
  char* Bdst = (char*)Bs + wid * 1024;

  const int fr = lane & 15, g = lane >> 4;
  const int swzR = (fr & 7) << 4;
  const char* Ard = (const char*)As + (wm + fr) * 128;
  const char* Brd = (const char*)Bs + (wn + fr) * 128;

  for (int k0 = 0; k0 < TH1_; k0 += 64) {
#pragma unroll
    for (int c = 0; c < 2; ++c)
      gload16(aS + (size_t)c * 64 * TH1_ + k0, Adst + c * 8192);
#pragma unroll
    for (int c = 0; c < 4; ++c)
      gload16(bS + (size_t)c * 64 * TH1_ + k0, Bdst + c * 8192);
    __syncthreads();
#pragma unroll
    for (int ks = 0; ks < 2; ++ks) {
      const int ca = (ks * 64 + g * 16) ^ swzR;
      bf16x8 af[4], bfv[4];
#pragma unroll
      for (int i = 0; i < 4; i++) af[i] = *(const bf16x8*)(Ard + i * 2048 + ca);
#pragma unroll
      for (int j = 0; j < 4; j++) bfv[j] = *(const bf16x8*)(Brd + j * 2048 + ca);
      __builtin_amdgcn_s_setprio(1);
#pragma unroll
      for (int i = 0; i < 4; i++)
#pragma unroll
        for (int j = 0; j < 4; j++)
          acc[i][j] = __builtin_amdgcn_mfma_f32_16x16x32_bf16(af[i], bfv[j], acc[i][j], 0, 0, 0);
      __builtin_amdgcn_s_setprio(0);
    }
    __syncthreads();
  }

  // epilogue: G2 val = relu(acc + bt2[col]); row-dot with Wt3 in-register.
  const int cc = lane & 15, cr4 = (lane >> 4) * 4;
  float w3v[4], b2v[4];
#pragma unroll
  for (int j = 0; j < 4; ++j) {
    const int col = wn + j * 16 + cc;
    w3v[j] = w3[t * TH2_ + col];
    b2v[j] = b2[t * TH2_ + col];
  }
#pragma unroll
  for (int i = 0; i < 4; ++i)
#pragma unroll
    for (int r = 0; r < 4; ++r) {
      float p = 0.f;
#pragma unroll
      for (int j = 0; j < 4; ++j) {
        float v = fmaxf(acc[i][j][r] + b2v[j], 0.f);
        p += v * w3v[j];
      }
      // reduce over the 16 cc lanes (same rows)
      p += __shfl_xor(p, 1, 64);
      p += __shfl_xor(p, 2, 64);
      p += __shfl_xor(p, 4, 64);
      p += __shfl_xor(p, 8, 64);
      if (cc == 0) ps[wid & 3][wm + i * 16 + cr4 + r] = p;
    }
  __syncthreads();
  if (tid < 128) {
    float s = ps[0][tid] + ps[1][tid] + ps[2][tid] + ps[3][tid] + b3[t];
    out[(size_t)t * B_ + b0 + m0 + tid] = s;
  }
}

extern "C" void kernel_launch(void* const* d_in, const int* in_sizes, int n_in,
                              void* d_out, int out_size, void* d_ws, size_t ws_size,
                              hipStream_t stream) {
  const float* x   = (const float*)d_in[0];
  const float* We1 = (const float*)d_in[1];
  const float* be1 = (const float*)d_in[2];
  const float* We2 = (const float*)d_in[3];
  const float* be2 = (const float*)d_in[4];
  const float* We3 = (const float*)d_in[5];
  const float* be3 = (const float*)d_in[6];
  const float* Wg  = (const float*)d_in[7];
  const float* Wt1 = (const float*)d_in[8];
  const float* bt1 = (const float*)d_in[9];
  const float* Wt2 = (const float*)d_in[10];
  const float* bt2 = (const float*)d_in[11];
  const float* Wt3 = (const float*)d_in[12];
  const float* bt3 = (const float*)d_in[13];
  float* out = (float*)d_out;
  (void)in_sizes; (void)n_in; (void)out_size;

  char* ws = (char*)d_ws;
  size_t off = 0;
  auto alloc = [&](size_t bytes) {
    char* p = ws + off;
    off += (bytes + 255) & ~(size_t)255;
    return p;
  };
  // ---- persistent region (~81 MB) ----
  short* We1b  = (short*)alloc((size_t)E_ * F_ * EH1_ * 2);
  short* We2b  = (short*)alloc((size_t)E_ * EH1_ * EH2_ * 2);
  short* We3b  = (short*)alloc((size_t)E_ * EH2_ * U_ * 2);
  short* Wt1b  = (short*)alloc((size_t)T_ * U_ * TH1_ * 2);
  short* Wt2b  = (short*)alloc((size_t)T_ * TH1_ * TH2_ * 2);
  short* Wgp   = (short*)alloc((size_t)32 * F_ * 2);
  short* Wgr   = (short*)alloc((size_t)32 * F_ * 2);
  float* gates = (float*)alloc((size_t)T_ * B_ * E_ * 4);
  short* xb    = (short*)alloc((size_t)B_ * F_ * 2);
  const size_t persist = off;

  // ---- mode select: full-tower (persistent ti) if ws allows ----
  const size_t tiBytes = ((size_t)T_ * B_ * U_ * 2 + 255) & ~(size_t)255;
  int Bc = 0;
  bool full = false;
  for (int bc = 16384; bc >= 4096; bc >>= 1) {
    if (persist + tiBytes + (size_t)bc * 32768 + 65536 <= ws_size) { Bc = bc; full = true; break; }
  }
  if (!full) {
    Bc = 16384;
    while (Bc > 256 && persist + (size_t)Bc * 32768 + 65536 > ws_size) Bc >>= 1;
  }
  const int bcShift = __builtin_ctz((unsigned)Bc);
  (void)bcShift;

  short* tiFull = full ? (short*)alloc((size_t)T_ * B_ * U_ * 2) : nullptr;
  short* h1 = (short*)alloc((size_t)E_ * Bc * EH1_ * 2);  // also EO / (full) G1 overlay
  short* h2 = (short*)alloc((size_t)E_ * Bc * EH2_ * 2);  // fallback: ti/G1 overlay
  short* EO = h1;
  short* tiC = h2;                              // fallback per-chunk ti
  short* G1C = h2 + (size_t)Bc * 2048;          // fallback per-chunk G1

  // ---- one-time conversions ----
  dim3 tb(32, 8);
  trans_conv<<<dim3(F_ / 32, EH1_ / 32, E_), tb, 0, stream>>>(We1, We1b, F_, EH1_);
  trans_conv<<<dim3(EH1_ / 32, EH2_ / 32, E_), tb, 0, stream>>>(We2, We2b, EH1_, EH2_);
  trans_conv<<<dim3(EH2_ / 32, U_ / 32, E_), tb, 0, stream>>>(We3, We3b, EH2_, U_);
  trans_conv<<<dim3(U_ / 32, TH1_ / 32, T_), tb, 0, stream>>>(Wt1, Wt1b, U_, TH1_);
  trans_conv<<<dim3(TH1_ / 32, TH2_ / 32, T_), tb, 0, stream>>>(Wt2, Wt2b, TH1_, TH2_);
  trans_wg<<<(32 * F_) / 256, 256, 0, stream>>>(Wg, Wgp, Wgr);

  // ---- fused x->bf16 conversion + 3-term MFMA gates ----
  prep_gates<<<B_ / 64, 256, 0, stream>>>(x, xb, Wgp, Wgr, gates);

  // ---- chunked expert pipeline ----
  for (int b0 = 0; b0 < B_; b0 += Bc) {
    const short* xc = xb + (size_t)b0 * F_;
    gemm_bt<1><<<dim3(Bc / 128, EH1_ / 128, E_), 256, 0, stream>>>(
        xc, 0, We1b, (size_t)F_ * EH1_, be1, EH1_, h1, (size_t)Bc * EH1_, Bc, EH1_, F_);
    gemm_bt<1><<<dim3(Bc / 128, EH2_ / 128, E_), 256, 0, stream>>>(
        h1, (size_t)Bc * EH1_, We2b, (size_t)EH1_ * EH2_, be2, EH2_, h2, (size_t)Bc * EH2_,
        Bc, EH2_, EH1_);
    gemm_bt<0><<<dim3(Bc / 128, U_ / 128, E_), 256, 0, stream>>>(
        h2, (size_t)Bc * EH2_, We3b, (size_t)EH2_ * U_, be3, U_, EO, (size_t)Bc * U_,
        Bc, U_, EH2_);
    if (full) {
      combine_kernel<<<(Bc * 64) / 256, 256, 0, stream>>>(EO, gates, tiFull, Bc, b0, B_, b0);
    } else {
      combine_kernel<<<(Bc * 64) / 256, 256, 0, stream>>>(EO, gates, tiC, Bc, b0, Bc, 0);
      gemm_bt<1><<<dim3(Bc / 128, TH1_ / 128, T_), 256, 0, stream>>>(
          tiC, (size_t)Bc * U_, Wt1b, (size_t)U_ * TH1_, bt1, TH1_, G1C, (size_t)Bc * TH1_,
          Bc, TH1_, U_);
      wt23<<<dim3(Bc / 128, 1, T_), 512, 0, stream>>>(
          G1C, (size_t)Bc * TH1_, Wt2b, bt2, Wt3, bt3, out, b0);
    }
  }

  // ---- full mode: one deep tower pass over all B ----
  if (full) {
    short* G1 = h1;  // chunk region dead; holds T*B_*TH1 bf16 (67 MB)
    gemm_bt<1><<<dim3(B_ / 128, TH1_ / 128, T_), 256, 0, stream>>>(
        tiFull, (size_t)B_ * U_, Wt1b, (size_t)U_ * TH1_, bt1, TH1_,
        G1, (size_t)B_ * TH1_, B_, TH1_, U_);
    wt23<<<dim3(B_ / 128, 1, T_), 512, 0, stream>>>(
        G1, (size_t)B_ * TH1_, Wt2b, bt2, Wt3, bt3, out, 0);
  }
}